// Round 13
// baseline (37.296 us; speedup 1.0000x reference)
//
#include <hip/hip_runtime.h>

// LBP forward: out[n,f,h,w] = sum_p 2^p * sigmoid((nb - ctr)/0.1)
//   c  = projection_map[f,p]; ky,kx = kernels[f,p,:] in {0,1,2}
//   nb  = xpad[n,c,h+ky-1,w+kx-1]  (zero pad of 1), ctr = x[n,c,h,w]
// N=32 D=64 H=56 W=56 F=128 P=4
//
// Round-13 = round-12 (no-LDS, L2-fed, XCD-pinned) with the OOB fixed:
// r12 masked the kx-edge AFTER the load -> lane 0 read x[-1] (page fault).
// Now the neighbor column index is CLAMPED per lane (w0=max(w-1,0),
// w2=min(w+1,55), selected under the wave-uniform kx branch) so every
// address stays inside a valid row; e0/e1 value-masks still zero the pad.
//   grid (32 n, 32): linear id % 8 == n % 8 -> XCD pin; per-XCD working set
//   4 x 0.8MB = 3.2MB < 4MB L2. Eval traffic (~411MB) served from L2.
// 512-thread blocks, no LDS, VGPR<=64 -> 8 waves/SIMD. Scalar addressing
// (c,ky,kx,f wave-uniform). 7-VALU trans-free sigmoid (r9/r11-verified).

#define NN 32
#define DD 64
#define HH 56
#define WW 56
#define FF 128
#define PP 4

#define ROWS 7            // output rows per strip
#define NSTRIP 8          // strips (8*7 = 56 rows)
#define NTHREADS 512      // 8 waves
#define FPB 32            // f per block (4 f-groups)
#define FPW 4             // f per wave (8 waves x 4 = 32)

__global__ __launch_bounds__(NTHREADS, 8) void lbp_kernel(
    const float* __restrict__ x,    // (N,D,H,W)
    const int*   __restrict__ kern, // (F,P,2)
    const int*   __restrict__ proj, // (F,P)
    float*       __restrict__ out)  // (N,F,H,W)
{
    const int tid   = threadIdx.x;
    const int n     = blockIdx.x;            // fastest grid dim -> id%8 = n%8
    const int strip = blockIdx.y >> 2;       // 0..7
    const int fg    = blockIdx.y & 3;        // 0..3
    const int h0    = strip * ROWS;

    const int wave = __builtin_amdgcn_readfirstlane(tid >> 6);  // 0..7
    const int lane = tid & 63;
    const int w    = lane < WW ? lane : WW - 1;   // clamp idle lanes
    const bool act = lane < WW;
    const bool e0  = (lane == 0);                 // left edge lane
    const bool e1  = (lane >= WW - 1);            // right edge (incl. clamps)

    const int w0 = (w > 0) ? (w - 1) : 0;         // clamped neighbor columns
    const int w2 = (w < WW - 1) ? (w + 1) : (WW - 1);

    const float* xn = x + (size_t)n * (DD * HH * WW);

    int f = fg * FPB + wave;                 // wave-uniform
    int4 pj = *(const int4*)(proj + f * PP);
    int4 ka = *(const int4*)(kern + f * (PP * 2));
    int4 kb = *(const int4*)(kern + f * (PP * 2) + 4);

#pragma unroll
    for (int k = 0; k < FPW; ++k) {
        const int fn = f + 8;                // next f for this wave
        int4 pjn, kan, kbn;
        if (k + 1 < FPW) {                   // one-ahead table prefetch
            pjn = *(const int4*)(proj + fn * PP);
            kan = *(const int4*)(kern + fn * (PP * 2));
            kbn = *(const int4*)(kern + fn * (PP * 2) + 4);
        }
        const int cc[4]  = {pj.x, pj.y, pj.z, pj.w};
        const int kyv[4] = {ka.x, ka.z, kb.x, kb.z};
        const int kxv[4] = {ka.y, ka.w, kb.y, kb.w};

        float acc[ROWS];
#pragma unroll
        for (int r = 0; r < ROWS; ++r) acc[r] = 7.5f;   // sum wt*0.5

#pragma unroll
        for (int p = 0; p < PP; ++p) {
            const int ky = kyv[p];           // SGPR, wave-uniform
            const int kx = kxv[p];
            // scalar bases (no kx term: column handled by clamped index)
            const float* cb = xn + cc[p] * (HH * WW) + h0 * WW;
            const float* nbase = cb + (ky - 1) * WW;
            const int wn = (kx == 0) ? w0 : ((kx == 2) ? w2 : w);

            // ---- loads: ctr (never OOB) + nb (row OOB wave-uniform) ----
            float cv[ROWS], nv[ROWS];
#pragma unroll
            for (int r = 0; r < ROWS; ++r)
                cv[r] = cb[r * WW + w];
            const bool topOOB = (strip == 0)          && (ky == 0);
            const bool botOOB = (strip == NSTRIP - 1) && (ky == 2);
#pragma unroll
            for (int r = 0; r < ROWS; ++r) {
                if ((r == 0 && topOOB) || (r == ROWS - 1 && botOOB))
                    nv[r] = 0.f;
                else
                    nv[r] = nbase[r * WW + wn];   // always in-bounds
            }
            // kx edge columns: zero the affected lane's value (uniform branch)
            if (kx == 0) {
#pragma unroll
                for (int r = 0; r < ROWS; ++r) nv[r] = e0 ? 0.f : nv[r];
            } else if (kx == 2) {
#pragma unroll
                for (int r = 0; r < ROWS; ++r) nv[r] = e1 ? 0.f : nv[r];
            }

            // ---- 7-VALU trans-free sigmoid accumulate ----
            const float wt = (float)(1 << p);
#pragma unroll
            for (int r = 0; r < ROWS; ++r) {
                const float d  = nv[r] - cv[r];
                const float ad = __builtin_fabsf(d);
                const float u0 = fmaf(2.5f,     ad, -0.0078f);
                const float u1 = fmaf(1.49146f, ad,  0.08455f);
                const float u2 = fmaf(0.45177f, ad,  0.30774f);
                const float um = fminf(fminf(fminf(u0, u1), u2), 0.49140f);
                acc[r] = fmaf(wt, __builtin_copysignf(um, d), acc[r]);
            }
        }

        if (act) {
            float* op = out + ((size_t)n * FF + f) * (HH * WW)
                            + (size_t)h0 * WW + w;
#pragma unroll
            for (int r = 0; r < ROWS; ++r) op[r * WW] = acc[r];
        }
        f = fn; pj = pjn; ka = kan; kb = kbn;
    }
}

extern "C" void kernel_launch(void* const* d_in, const int* in_sizes, int n_in,
                              void* d_out, int out_size, void* d_ws, size_t ws_size,
                              hipStream_t stream) {
    const float* x    = (const float*)d_in[0];
    const int*   kern = (const int*)d_in[1];
    const int*   proj = (const int*)d_in[2];
    float*       out  = (float*)d_out;

    dim3 grid(NN, NSTRIP * 4);   // x = n (XCD pin: id%8 = n%8), y = strip*4+fg
    dim3 block(NTHREADS);
    lbp_kernel<<<grid, block, 0, stream>>>(x, kern, proj, out);
}

// Round 14
// 30.510 us; speedup vs baseline: 1.2224x; 1.2224x over previous
//
#include <hip/hip_runtime.h>

// LBP forward: out[n,f,h,w] = sum_p 2^p * sigmoid((nb - ctr)/0.1)
//   c  = projection_map[f,p]; ky,kx = kernels[f,p,:] in {0,1,2}
//   nb  = xpad[n,c,h+ky-1,w+kx-1]  (zero pad of 1), ctr = x[n,c,h,w]
// N=32 D=64 H=56 W=56 F=128 P=4
//
// Round-14: LDS-port bound fixed by b128-everything + same-channel reuse.
//  - tile[ch][colp 0..57][slot 8 rows] fp32, 32B slots => ds_read_b128 pairs
//    give rows h0..h0+6 (+1 junk) of one column in 2 instrs. 118,784 B LDS.
//  - ctr and nb share the channel: kx==1 -> nb comes from the SAME two b128s
//    as ctr (zero extra LDS); kx!=1 -> 2 more b128 at col w+kx (per-lane addr).
//    Vertical ky shift = register selection (wave-uniform branch, 0 VALU).
//  - XOR swizzle of byte bits 4-5 by (colp>>2)&3 (write AND read) spreads the
//    32B-stride columns across all 8 bank-quads; preserves 16B alignment.
//  - Halo rows (h0-1, h0+7) are NOT in the tile: the <=1 edge row per (f,p)
//    is a per-lane global load hitting XCD-local L2 (grid x=n -> id%8=n%8 pin;
//    neighbor strips of n stage those rows on the same XCD).
//  - Zero-pad columns 0 and 57 replace all kx edge masking in the hot loop.
//  - 7-VALU trans-free sigmoid (r9/r11-verified, absmax 0.1875 < 0.3).
// Grid 8x32 = 256 blocks = 1/CU; 16 waves; wave-uniform f via readfirstlane,
// s_load tables one-ahead prefetched.

#define NN 32
#define DD 64
#define HH 56
#define WW 56
#define FF 128
#define PP 4

#define ROWS 7
#define NSTRIP 8
#define NTHREADS 1024
#define NWAVES 16
#define FITER (FF / NWAVES)   // 8
#define NCOLP 58              // pad col, 56 data cols, pad col
#define SLOT  8               // dwords per (ch,col): rows 0..6 + junk
#define CHDW  (NCOLP * SLOT)  // 464 dwords per channel
#define TILE_DW (DD * CHDW)   // 29696 dwords = 118784 B
#define NITEMS (DD * ROWS * 14)  // 6272 staging float4 items

__device__ __forceinline__ int swzb(int colp) { return ((colp >> 2) & 3) << 4; }

__global__ __launch_bounds__(NTHREADS, 4) void lbp_kernel(
    const float* __restrict__ x,    // (N,D,H,W)
    const int*   __restrict__ kern, // (F,P,2)
    const int*   __restrict__ proj, // (F,P)
    float*       __restrict__ out)  // (N,F,H,W)
{
    __shared__ float tile[TILE_DW];
    char* tb = (char*)tile;

    const int tid   = threadIdx.x;
    const int n     = blockIdx.x;       // fastest -> linear id % 8 = n % 8
    const int strip = blockIdx.y;       // 0..7
    const int h0    = strip * ROWS;

    const float* xn = x + (size_t)n * (DD * HH * WW);

    // ---- stage: issue all loads first (7 float4/thread) ----
    float4 rv[7];
#pragma unroll
    for (int it = 0; it < 7; ++it) {
        const int item = tid + it * NTHREADS;
        if (item < NITEMS) {
            const int ch  = item / (ROWS * 14);
            const int rem = item - ch * (ROWS * 14);
            const int r   = rem / 14;
            const int g   = rem - r * 14;
            rv[it] = *(const float4*)(xn + ch * (HH * WW) + (h0 + r) * WW + 4 * g);
        }
    }

    // ---- zero pad columns 0 and 57 (all 8 slot rows) while loads fly ----
    if (tid < 256) {
        const int ch   = tid >> 2;
        const int colp = ((tid >> 1) & 1) ? 57 : 0;
        const int half = tid & 1;
        const int b = (((ch * NCOLP + colp) * SLOT) * 4 + half * 16) ^ swzb(colp);
        *(float4*)(tb + b) = make_float4(0.f, 0.f, 0.f, 0.f);
    }

    // ---- transpose-write into swizzled col-major slots ----
#pragma unroll
    for (int it = 0; it < 7; ++it) {
        const int item = tid + it * NTHREADS;
        if (item < NITEMS) {
            const int ch  = item / (ROWS * 14);
            const int rem = item - ch * (ROWS * 14);
            const int r   = rem / 14;
            const int g   = rem - r * 14;
            const float4 v = rv[it];
            const int base = ch * CHDW + r;     // + colp*SLOT per element
#pragma unroll
            for (int j = 0; j < 4; ++j) {
                const int colp = 1 + 4 * g + j;
                const float e = (j == 0) ? v.x : (j == 1) ? v.y : (j == 2) ? v.z : v.w;
                const int b = ((base + colp * SLOT) * 4) ^ swzb(colp);
                *(float*)(tb + b) = e;
            }
        }
    }
    __syncthreads();

    // ---- compute: wave = f, lane = column ----
    const int wid  = __builtin_amdgcn_readfirstlane(tid >> 6);  // 0..15
    const int lane = tid & 63;
    const int w    = (lane < WW) ? lane : (lane - WW);  // idle lanes -> cols 0..7
    const bool act = lane < WW;

    int f = wid;
    int4 pj = *(const int4*)(proj + f * PP);
    int4 ka = *(const int4*)(kern + f * (PP * 2));
    int4 kb = *(const int4*)(kern + f * (PP * 2) + 4);

#pragma unroll
    for (int k = 0; k < FITER; ++k) {
        const int fn = f + NWAVES;
        int4 pjn, kan, kbn;
        if (fn < FF) {                 // one-ahead table prefetch (s_load)
            pjn = *(const int4*)(proj + fn * PP);
            kan = *(const int4*)(kern + fn * (PP * 2));
            kbn = *(const int4*)(kern + fn * (PP * 2) + 4);
        }
        const int cc[4]  = {pj.x, pj.y, pj.z, pj.w};
        const int kyv[4] = {ka.x, ka.z, kb.x, kb.z};
        const int kxv[4] = {ka.y, ka.w, kb.y, kb.w};

        float acc[ROWS];
#pragma unroll
        for (int r = 0; r < ROWS; ++r) acc[r] = 7.5f;   // sum wt*0.5

#pragma unroll
        for (int p = 0; p < PP; ++p) {
            const int c  = cc[p];      // SGPR, wave-uniform
            const int ky = kyv[p];
            const int kx = kxv[p];

            // ---- halo row from global/L2 (at most one per p) ----
            float gt = 0.f, gb = 0.f;
            if (ky == 0) {
                if (strip > 0) {
                    int wn = w + kx - 1; wn = (wn < 0) ? 0 : (wn > 55 ? 55 : wn);
                    gt = xn[c * (HH * WW) + (h0 - 1) * WW + wn];
                    if (kx == 0) gt = (lane == 0) ? 0.f : gt;
                    if (kx == 2) gt = (lane == 55) ? 0.f : gt;
                }
            } else if (ky == 2) {
                if (strip < NSTRIP - 1) {
                    int wn = w + kx - 1; wn = (wn < 0) ? 0 : (wn > 55 ? 55 : wn);
                    gb = xn[c * (HH * WW) + (h0 + ROWS) * WW + wn];
                    if (kx == 0) gb = (lane == 0) ? 0.f : gb;
                    if (kx == 2) gb = (lane == 55) ? 0.f : gb;
                }
            }

            // ---- ctr column (colp = w+1): 2x ds_read_b128 ----
            const int cp  = w + 1;
            const int cb0 = ((c * CHDW + cp * SLOT) * 4);
            const float4 c0 = *(const float4*)(tb + ((cb0)      ^ swzb(cp)));
            const float4 c1 = *(const float4*)(tb + ((cb0 + 16) ^ swzb(cp)));

            // ---- nb column: reuse ctr regs when kx==1 ----
            float4 n0 = c0, n1 = c1;
            if (kx != 1) {
                const int cq  = w + kx;            // colp of neighbor (0/57 = pad)
                const int nb0 = ((c * CHDW + cq * SLOT) * 4);
                n0 = *(const float4*)(tb + ((nb0)      ^ swzb(cq)));
                n1 = *(const float4*)(tb + ((nb0 + 16) ^ swzb(cq)));
            }

            const float C[ROWS] = {c0.x, c0.y, c0.z, c0.w, c1.x, c1.y, c1.z};
            float Nv[ROWS];
            if (ky == 0) {          // nb row = slot r-1; r=0 -> halo
                Nv[0] = gt;   Nv[1] = n0.x; Nv[2] = n0.y; Nv[3] = n0.z;
                Nv[4] = n0.w; Nv[5] = n1.x; Nv[6] = n1.y;
            } else if (ky == 1) {   // nb row = slot r
                Nv[0] = n0.x; Nv[1] = n0.y; Nv[2] = n0.z; Nv[3] = n0.w;
                Nv[4] = n1.x; Nv[5] = n1.y; Nv[6] = n1.z;
            } else {                // nb row = slot r+1; r=6 -> halo
                Nv[0] = n0.y; Nv[1] = n0.z; Nv[2] = n0.w; Nv[3] = n1.x;
                Nv[4] = n1.y; Nv[5] = n1.z; Nv[6] = gb;
            }

            // ---- 7-VALU trans-free sigmoid accumulate ----
            const float wt = (float)(1 << p);
#pragma unroll
            for (int r = 0; r < ROWS; ++r) {
                const float d  = Nv[r] - C[r];
                const float ad = __builtin_fabsf(d);
                const float u0 = fmaf(2.5f,     ad, -0.0078f);
                const float u1 = fmaf(1.49146f, ad,  0.08455f);
                const float u2 = fmaf(0.45177f, ad,  0.30774f);
                const float um = fminf(fminf(fminf(u0, u1), u2), 0.49140f);
                acc[r] = fmaf(wt, __builtin_copysignf(um, d), acc[r]);
            }
        }

        if (act) {
            float* op = out + ((size_t)n * FF + f) * (HH * WW)
                            + (size_t)h0 * WW + w;
#pragma unroll
            for (int r = 0; r < ROWS; ++r) op[r * WW] = acc[r];
        }
        f = fn; pj = pjn; ka = kan; kb = kbn;
    }
}

extern "C" void kernel_launch(void* const* d_in, const int* in_sizes, int n_in,
                              void* d_out, int out_size, void* d_ws, size_t ws_size,
                              hipStream_t stream) {
    const float* x    = (const float*)d_in[0];
    const int*   kern = (const int*)d_in[1];
    const int*   proj = (const int*)d_in[2];
    float*       out  = (float*)d_out;

    dim3 grid(NN, NSTRIP);   // x = n (XCD pin: id%8 = n%8), y = strip
    dim3 block(NTHREADS);
    lbp_kernel<<<grid, block, 0, stream>>>(x, kern, proj, out);
}